// Round 1
// baseline (183.616 us; speedup 1.0000x reference)
//
#include <hip/hip_runtime.h>
#include <cmath>

typedef unsigned short u16;
typedef unsigned int u32;
typedef __bf16 bf16x8 __attribute__((ext_vector_type(8)));
typedef float f32x4 __attribute__((ext_vector_type(4)));

#define NQ (768*768)   // 589824  (Wq, Wo element count)
#define NK (384*768)   // 294912  (Wk, Wv element count)

// ---------- helpers ----------
__device__ __forceinline__ u16 f2bf(float f) {
  u32 u = __float_as_uint(f);
  u32 r = (u + 0x7FFFu + ((u >> 16) & 1u)) >> 16;  // RNE
  return (u16)r;
}
__device__ __forceinline__ void ld16g(int4* dst, const void* p) { __builtin_memcpy(dst, p, 16); }
__device__ __forceinline__ bf16x8 ldfrag(const u16* p) { bf16x8 v; __builtin_memcpy(&v, p, 16); return v; }
__device__ __forceinline__ f32x4 mfma_(bf16x8 a, bf16x8 b, f32x4 c) {
  return __builtin_amdgcn_mfma_f32_16x16x32_bf16(a, b, c, 0, 0, 0);
}

// ---------- 1) sum(|w|) per matrix ----------
__global__ __launch_bounds__(256) void abssum_kernel(const float* __restrict__ wq, const float* __restrict__ wk,
                                                     const float* __restrict__ wv, const float* __restrict__ wo,
                                                     float* __restrict__ sums) {
  int which = blockIdx.y;
  const float* w = (which == 0) ? wq : (which == 1) ? wk : (which == 2) ? wv : wo;
  int n4 = ((which == 0 || which == 3) ? NQ : NK) >> 2;
  const float4* w4 = (const float4*)w;
  float s = 0.f;
  for (int i = blockIdx.x * blockDim.x + threadIdx.x; i < n4; i += gridDim.x * blockDim.x) {
    float4 v = w4[i];
    s += fabsf(v.x) + fabsf(v.y) + fabsf(v.z) + fabsf(v.w);
  }
  for (int off = 32; off; off >>= 1) s += __shfl_down(s, off);
  __shared__ float ls[4];
  if ((threadIdx.x & 63) == 0) ls[threadIdx.x >> 6] = s;
  __syncthreads();
  if (threadIdx.x == 0) atomicAdd(&sums[which], ls[0] + ls[1] + ls[2] + ls[3]);
}

// ---------- 2) ternary quantize to bf16 {-1,0,1} ----------
// qw rows: [0,768) = Wq, [768,1152) = Wk, [1152,1536) = Wv  (flat-index contiguous)
__global__ __launch_bounds__(256) void quant_kernel(const float* __restrict__ wq, const float* __restrict__ wk,
                                                    const float* __restrict__ wv, const float* __restrict__ wo,
                                                    const float* __restrict__ sums,
                                                    u16* __restrict__ qw, u16* __restrict__ woq) {
  float thr0 = 0.7f * sums[0] * (1.f / NQ);
  float thr1 = 0.7f * sums[1] * (1.f / NK);
  float thr2 = 0.7f * sums[2] * (1.f / NK);
  float thr3 = 0.7f * sums[3] * (1.f / NQ);
  const int NQKV = NQ + 2 * NK;  // 1179648
  const int total = NQKV + NQ;   // 1769472
  for (int i = blockIdx.x * blockDim.x + threadIdx.x; i < total; i += gridDim.x * blockDim.x) {
    float v, th; u16* dst;
    if (i < NQ)            { v = wq[i];            th = thr0; dst = &qw[i]; }
    else if (i < NQ + NK)  { v = wk[i - NQ];       th = thr1; dst = &qw[i]; }
    else if (i < NQKV)     { v = wv[i - NQ - NK];  th = thr2; dst = &qw[i]; }
    else                   { v = wo[i - NQKV];     th = thr3; dst = &woq[i - NQKV]; }
    float q = (fabsf(v) >= th) ? ((v > 0.f) ? 1.f : -1.f) : 0.f;
    *dst = f2bf(q);
  }
}

// ---------- 3) x -> bf16 ----------
__global__ __launch_bounds__(256) void castx_kernel(const float* __restrict__ x, u16* __restrict__ xb) {
  int i = blockIdx.x * blockDim.x + threadIdx.x;  // one float4 per thread, exact cover
  float4 v = ((const float4*)x)[i];
  u16 o[4] = { f2bf(v.x), f2bf(v.y), f2bf(v.z), f2bf(v.w) };
  __builtin_memcpy(&xb[i * 4], o, 8);
}

// ---------- 4) fused QKV GEMM + scale + RoPE + V transpose ----------
// C[m][n] = sum_k xb[m][k] * qw[n][k], m in [0,4096), n in [0,1536), k in [0,768)
// tiles: 64x64, BK=64, 4 waves each 16 rows. MFMA 16x16x32 bf16.
// A-frag: A[m=lane&15][k=(lane>>4)*8+j]; B-frag: B[n=lane&15][k=(lane>>4)*8+j] (W is [n][k])
// C/D:    row=(lane>>4)*4+reg, col=lane&15   [verified m89]
__global__ __launch_bounds__(256) void gemm_qkv_kernel(const u16* __restrict__ xb, const u16* __restrict__ qw,
                                                       const float* __restrict__ sums,
                                                       u16* __restrict__ qb, u16* __restrict__ kb,
                                                       u16* __restrict__ vT) {
  __shared__ u16 At[64][72];
  __shared__ u16 Bt[64][72];
  int tn = blockIdx.x, tm = blockIdx.y;
  int t = threadIdx.x, lane = t & 63, w = t >> 6, l15 = lane & 15, g = lane >> 4;
  f32x4 zero = {0.f, 0.f, 0.f, 0.f};
  f32x4 acc[4] = {zero, zero, zero, zero};
  int r = t >> 2, c0 = (t & 3) * 16;
  const u16* arow = xb + (tm * 64 + r) * 768;
  const u16* brow = qw + (tn * 64 + r) * 768;
  for (int k0 = 0; k0 < 768; k0 += 64) {
    int4 a0, a1, b0, b1;
    ld16g(&a0, arow + k0 + c0); ld16g(&a1, arow + k0 + c0 + 8);
    ld16g(&b0, brow + k0 + c0); ld16g(&b1, brow + k0 + c0 + 8);
    __builtin_memcpy(&At[r][c0], &a0, 16); __builtin_memcpy(&At[r][c0 + 8], &a1, 16);
    __builtin_memcpy(&Bt[r][c0], &b0, 16); __builtin_memcpy(&Bt[r][c0 + 8], &b1, 16);
    __syncthreads();
    for (int ks = 0; ks < 2; ks++) {
      bf16x8 a = ldfrag(&At[w * 16 + l15][ks * 32 + g * 8]);
#pragma unroll
      for (int ct = 0; ct < 4; ct++) {
        bf16x8 b = ldfrag(&Bt[ct * 16 + l15][ks * 32 + g * 8]);
        acc[ct] = mfma_(a, b, acc[ct]);
      }
    }
    __syncthreads();
  }
  float sq = sums[0] * (1.f / NQ);
  float sk = sums[1] * (1.f / NK);
  float sv = sums[2] * (1.f / NK);
  int mbase = tm * 64 + w * 16 + g * 4;
  if (tn < 18) {
    // q (tn<12) or k (12<=tn<18): apply scale + RoPE, write [row][head*64+d]
    float sc = (tn < 12) ? sq : sk;
    int head = (tn < 12) ? tn : tn - 12;
    u16* outp = (tn < 12) ? qb : kb;
    int stride = (tn < 12) ? 768 : 384;
#pragma unroll
    for (int ct = 0; ct < 2; ct++) {
      int i = ct * 16 + l15;  // d in [0,32): pairs with d+32 held in frag ct+2, same lane
      float f = (float)pow(10000.0, -(double)i * (1.0 / 32.0));
      for (int rr = 0; rr < 4; rr++) {
        int m = mbase + rr; int s = m & 2047;
        float ang = (float)s * f;
        float sn, cs; sincosf(ang, &sn, &cs);
        float x1 = acc[ct][rr] * sc, x2 = acc[ct + 2][rr] * sc;
        outp[m * stride + head * 64 + i]      = f2bf(x1 * cs - x2 * sn);
        outp[m * stride + head * 64 + i + 32] = f2bf(x2 * cs + x1 * sn);
      }
    }
  } else {
    // v: scale + store transposed vT[((b*6+kvh)*64 + d)*2048 + s]
    int kvh = tn - 18;
#pragma unroll
    for (int ct = 0; ct < 4; ct++) {
      int d = ct * 16 + l15;
      for (int rr = 0; rr < 4; rr++) {
        int m = mbase + rr; int bb = m >> 11; int s = m & 2047;
        vT[((bb * 6 + kvh) * 64 + d) * 2048 + s] = f2bf(acc[ct][rr] * sv);
      }
    }
  }
}

// ---------- 5) attention: one-pass streaming softmax (no max subtraction; |logit| <~ 1) ----------
// grid (32 q-tiles, 24 b*h). block 256 = 4 waves, each wave: 16 q-rows x full 64-dim output.
__global__ __launch_bounds__(256) void attn_kernel(const u16* __restrict__ qb, const u16* __restrict__ kb,
                                                   const u16* __restrict__ vT, u16* __restrict__ ab) {
  __shared__ u16 Kt[64][72];        // [key][d]
  __shared__ u16 Vt[64][72];        // [d][key]  (from pre-transposed vT)
  __shared__ u16 Pt[4][16][72];     // per-wave P: [qrow][key]
  int qt = blockIdx.x, bh = blockIdx.y;
  int b = bh / 12, h = bh % 12, kvh = h >> 1;
  int t = threadIdx.x, lane = t & 63, w = t >> 6, l15 = lane & 15, g = lane >> 4;
  bf16x8 aq[2];
  {
    int qrow = b * 2048 + qt * 64 + w * 16 + l15;
    aq[0] = ldfrag(&qb[qrow * 768 + h * 64 + g * 8]);
    aq[1] = ldfrag(&qb[qrow * 768 + h * 64 + 32 + g * 8]);
  }
  f32x4 zero = {0.f, 0.f, 0.f, 0.f};
  f32x4 oacc[4] = {zero, zero, zero, zero};
  float lsum[4] = {0.f, 0.f, 0.f, 0.f};
  int r = t >> 2, c0 = (t & 3) * 16;
  const u16* kbase = kb + (b * 2048) * 384 + kvh * 64;
  const u16* vbase = vT + ((b * 6 + kvh) * 64 + r) * 2048;
  for (int kt = 0; kt < 32; kt++) {
    __syncthreads();   // all waves done reading Kt/Vt from prev iter
    int4 k0v, k1v, v0v, v1v;
    ld16g(&k0v, kbase + (kt * 64 + r) * 384 + c0);
    ld16g(&k1v, kbase + (kt * 64 + r) * 384 + c0 + 8);
    ld16g(&v0v, vbase + kt * 64 + c0);
    ld16g(&v1v, vbase + kt * 64 + c0 + 8);
    __builtin_memcpy(&Kt[r][c0], &k0v, 16); __builtin_memcpy(&Kt[r][c0 + 8], &k1v, 16);
    __builtin_memcpy(&Vt[r][c0], &v0v, 16); __builtin_memcpy(&Vt[r][c0 + 8], &v1v, 16);
    __syncthreads();
    // S = Q K^T  (C-layout: row g*4+rr = qrow, col ct*16+l15 = key)
    f32x4 sacc[4] = {zero, zero, zero, zero};
    for (int ks = 0; ks < 2; ks++) {
#pragma unroll
      for (int ct = 0; ct < 4; ct++) {
        bf16x8 bk = ldfrag(&Kt[ct * 16 + l15][ks * 32 + g * 8]);
        sacc[ct] = mfma_(aq[ks], bk, sacc[ct]);
      }
    }
    // P = exp(S/8), accumulate row sums, round-trip C-layout -> A-layout via LDS
#pragma unroll
    for (int ct = 0; ct < 4; ct++) {
#pragma unroll
      for (int rr = 0; rr < 4; rr++) {
        float p = __expf(sacc[ct][rr] * 0.125f);
        lsum[rr] += p;
        Pt[w][g * 4 + rr][ct * 16 + l15] = f2bf(p);
      }
    }
    __syncthreads();
    // O += P V   (B-frag from Vt: n=d=ct*16+l15 row, k=key contiguous)
    for (int ks = 0; ks < 2; ks++) {
      bf16x8 ap = ldfrag(&Pt[w][l15][ks * 32 + g * 8]);
#pragma unroll
      for (int ct = 0; ct < 4; ct++) {
        bf16x8 bv = ldfrag(&Vt[ct * 16 + l15][ks * 32 + g * 8]);
        oacc[ct] = mfma_(ap, bv, oacc[ct]);
      }
    }
  }
  // full row sums: reduce over the 16 lanes sharing g (bits 0..3)
#pragma unroll
  for (int rr = 0; rr < 4; rr++) {
    float v = lsum[rr];
    v += __shfl_xor(v, 1); v += __shfl_xor(v, 2); v += __shfl_xor(v, 4); v += __shfl_xor(v, 8);
    lsum[rr] = v;
  }
  int mbase = b * 2048 + qt * 64 + w * 16 + g * 4;
#pragma unroll
  for (int ct = 0; ct < 4; ct++)
    for (int rr = 0; rr < 4; rr++)
      ab[(mbase + rr) * 768 + h * 64 + ct * 16 + l15] = f2bf(oacc[ct][rr] / lsum[rr]);
}

// ---------- 6) output projection GEMM -> fp32 ----------
__global__ __launch_bounds__(256) void gemm_out_kernel(const u16* __restrict__ ab, const u16* __restrict__ woq,
                                                       const float* __restrict__ sums, float* __restrict__ out) {
  __shared__ u16 At[64][72];
  __shared__ u16 Bt[64][72];
  int tn = blockIdx.x, tm = blockIdx.y;
  int t = threadIdx.x, lane = t & 63, w = t >> 6, l15 = lane & 15, g = lane >> 4;
  f32x4 zero = {0.f, 0.f, 0.f, 0.f};
  f32x4 acc[4] = {zero, zero, zero, zero};
  int r = t >> 2, c0 = (t & 3) * 16;
  const u16* arow = ab + (tm * 64 + r) * 768;
  const u16* brow = woq + (tn * 64 + r) * 768;
  for (int k0 = 0; k0 < 768; k0 += 64) {
    int4 a0, a1, b0, b1;
    ld16g(&a0, arow + k0 + c0); ld16g(&a1, arow + k0 + c0 + 8);
    ld16g(&b0, brow + k0 + c0); ld16g(&b1, brow + k0 + c0 + 8);
    __builtin_memcpy(&At[r][c0], &a0, 16); __builtin_memcpy(&At[r][c0 + 8], &a1, 16);
    __builtin_memcpy(&Bt[r][c0], &b0, 16); __builtin_memcpy(&Bt[r][c0 + 8], &b1, 16);
    __syncthreads();
    for (int ks = 0; ks < 2; ks++) {
      bf16x8 a = ldfrag(&At[w * 16 + l15][ks * 32 + g * 8]);
#pragma unroll
      for (int ct = 0; ct < 4; ct++) {
        bf16x8 b = ldfrag(&Bt[ct * 16 + l15][ks * 32 + g * 8]);
        acc[ct] = mfma_(a, b, acc[ct]);
      }
    }
    __syncthreads();
  }
  float so = sums[3] * (1.f / NQ);
  int mbase = tm * 64 + w * 16 + g * 4;
#pragma unroll
  for (int ct = 0; ct < 4; ct++)
    for (int rr = 0; rr < 4; rr++)
      out[(mbase + rr) * 768 + tn * 64 + ct * 16 + l15] = acc[ct][rr] * so;
}

// ---------- launch ----------
extern "C" void kernel_launch(void* const* d_in, const int* in_sizes, int n_in,
                              void* d_out, int out_size, void* d_ws, size_t ws_size,
                              hipStream_t stream) {
  const float* x  = (const float*)d_in[0];
  const float* wq = (const float*)d_in[1];
  const float* wk = (const float*)d_in[2];
  const float* wv = (const float*)d_in[3];
  const float* wo = (const float*)d_in[4];
  float* out = (float*)d_out;
  char* ws = (char*)d_ws;

  // ws layout (bytes, 256-aligned): total ~27.4 MB
  float* sums = (float*)ws;                    // 16 B, zeroed below
  u16* qw  = (u16*)(ws + 256);                 // [1536][768] ternary bf16   2359296 B
  u16* woq = (u16*)(ws + 2359552);             // [768][768]                 1179648 B
  u16* xb  = (u16*)(ws + 3539200);             // [4096][768] bf16 x         6291456 B
  u16* qb  = (u16*)(ws + 9830656);             // [4096][768] roped q        6291456 B
  u16* kb  = (u16*)(ws + 16122112);            // [4096][384] roped k        3145728 B
  u16* vT  = (u16*)(ws + 19267840);            // [2*6][64][2048] v^T        3145728 B
  u16* ab  = (u16*)(ws + 22413568);            // [4096][768] attn out       6291456 B

  hipMemsetAsync(sums, 0, 16, stream);
  dim3 blk(256);
  abssum_kernel<<<dim3(64, 4), blk, 0, stream>>>(wq, wk, wv, wo, sums);
  quant_kernel<<<dim3(6912), blk, 0, stream>>>(wq, wk, wv, wo, sums, qw, woq);
  castx_kernel<<<dim3(3072), blk, 0, stream>>>(x, xb);
  gemm_qkv_kernel<<<dim3(24, 64), blk, 0, stream>>>(xb, qw, sums, qb, kb, vT);
  attn_kernel<<<dim3(32, 24), blk, 0, stream>>>(qb, kb, vT, ab);
  gemm_out_kernel<<<dim3(12, 64), blk, 0, stream>>>(ab, woq, sums, out);
}

// Round 2
// 178.462 us; speedup vs baseline: 1.0289x; 1.0289x over previous
//
#include <hip/hip_runtime.h>
#include <cmath>

typedef unsigned short u16;
typedef unsigned int u32;
typedef __bf16 bf16x2 __attribute__((ext_vector_type(2)));
typedef __bf16 bf16x8 __attribute__((ext_vector_type(8)));
typedef float f32x4 __attribute__((ext_vector_type(4)));
typedef float f32x16 __attribute__((ext_vector_type(16)));

#define NQ (768*768)   // 589824  (Wq, Wo element count)
#define NK (384*768)   // 294912  (Wk, Wv element count)

// ---------- helpers ----------
__device__ __forceinline__ u16 f2bf(float f) {
  u32 u = __float_as_uint(f);
  u32 r = (u + 0x7FFFu + ((u >> 16) & 1u)) >> 16;  // RNE
  return (u16)r;
}
__device__ __forceinline__ u32 packbf(float a, float b) {
#if __has_builtin(__builtin_amdgcn_cvt_pk_bf16_f32)
  bf16x2 v = __builtin_amdgcn_cvt_pk_bf16_f32(a, b);
  u32 r; __builtin_memcpy(&r, &v, 4); return r;
#else
  return (u32)f2bf(a) | ((u32)f2bf(b) << 16);
#endif
}
__device__ __forceinline__ float fexp2(float x) {
#if __has_builtin(__builtin_amdgcn_exp2f)
  return __builtin_amdgcn_exp2f(x);
#else
  return exp2f(x);
#endif
}
__device__ __forceinline__ void ld16g(int4* dst, const void* p) { __builtin_memcpy(dst, p, 16); }
__device__ __forceinline__ bf16x8 ldfrag(const u16* p) { bf16x8 v; __builtin_memcpy(&v, p, 16); return v; }
__device__ __forceinline__ f32x4 mfma_(bf16x8 a, bf16x8 b, f32x4 c) {
  return __builtin_amdgcn_mfma_f32_16x16x32_bf16(a, b, c, 0, 0, 0);
}
__device__ __forceinline__ f32x16 mfma32_(bf16x8 a, bf16x8 b, f32x16 c) {
  return __builtin_amdgcn_mfma_f32_32x32x16_bf16(a, b, c, 0, 0, 0);
}

// ---------- 1) sum(|w|) per matrix ----------
__global__ __launch_bounds__(256) void abssum_kernel(const float* __restrict__ wq, const float* __restrict__ wk,
                                                     const float* __restrict__ wv, const float* __restrict__ wo,
                                                     float* __restrict__ sums) {
  int which = blockIdx.y;
  const float* w = (which == 0) ? wq : (which == 1) ? wk : (which == 2) ? wv : wo;
  int n4 = ((which == 0 || which == 3) ? NQ : NK) >> 2;
  const float4* w4 = (const float4*)w;
  float s = 0.f;
  for (int i = blockIdx.x * blockDim.x + threadIdx.x; i < n4; i += gridDim.x * blockDim.x) {
    float4 v = w4[i];
    s += fabsf(v.x) + fabsf(v.y) + fabsf(v.z) + fabsf(v.w);
  }
  for (int off = 32; off; off >>= 1) s += __shfl_down(s, off);
  __shared__ float ls[4];
  if ((threadIdx.x & 63) == 0) ls[threadIdx.x >> 6] = s;
  __syncthreads();
  if (threadIdx.x == 0) atomicAdd(&sums[which], ls[0] + ls[1] + ls[2] + ls[3]);
}

// ---------- 2) ternary quantize to bf16 {-1,0,1} ----------
__global__ __launch_bounds__(256) void quant_kernel(const float* __restrict__ wq, const float* __restrict__ wk,
                                                    const float* __restrict__ wv, const float* __restrict__ wo,
                                                    const float* __restrict__ sums,
                                                    u16* __restrict__ qw, u16* __restrict__ woq) {
  float thr0 = 0.7f * sums[0] * (1.f / NQ);
  float thr1 = 0.7f * sums[1] * (1.f / NK);
  float thr2 = 0.7f * sums[2] * (1.f / NK);
  float thr3 = 0.7f * sums[3] * (1.f / NQ);
  const int NQKV = NQ + 2 * NK;  // 1179648
  const int total = NQKV + NQ;   // 1769472
  for (int i = blockIdx.x * blockDim.x + threadIdx.x; i < total; i += gridDim.x * blockDim.x) {
    float v, th; u16* dst;
    if (i < NQ)            { v = wq[i];            th = thr0; dst = &qw[i]; }
    else if (i < NQ + NK)  { v = wk[i - NQ];       th = thr1; dst = &qw[i]; }
    else if (i < NQKV)     { v = wv[i - NQ - NK];  th = thr2; dst = &qw[i]; }
    else                   { v = wo[i - NQKV];     th = thr3; dst = &woq[i - NQKV]; }
    float q = (fabsf(v) >= th) ? ((v > 0.f) ? 1.f : -1.f) : 0.f;
    *dst = f2bf(q);
  }
}

// ---------- 3) x -> bf16 ----------
__global__ __launch_bounds__(256) void castx_kernel(const float* __restrict__ x, u16* __restrict__ xb) {
  int i = blockIdx.x * blockDim.x + threadIdx.x;
  float4 v = ((const float4*)x)[i];
  u16 o[4] = { f2bf(v.x), f2bf(v.y), f2bf(v.z), f2bf(v.w) };
  __builtin_memcpy(&xb[i * 4], o, 8);
}

// ---------- 4) fused QKV GEMM + scale + RoPE + V transpose ----------
// Q is additionally scaled by 0.125*log2(e) so attention uses raw exp2.
__global__ __launch_bounds__(256) void gemm_qkv_kernel(const u16* __restrict__ xb, const u16* __restrict__ qw,
                                                       const float* __restrict__ sums,
                                                       u16* __restrict__ qb, u16* __restrict__ kb,
                                                       u16* __restrict__ vT) {
  __shared__ u16 At[64][72];
  __shared__ u16 Bt[64][72];
  int tn = blockIdx.x, tm = blockIdx.y;
  int t = threadIdx.x, lane = t & 63, w = t >> 6, l15 = lane & 15, g = lane >> 4;
  f32x4 zero = {0.f, 0.f, 0.f, 0.f};
  f32x4 acc[4] = {zero, zero, zero, zero};
  int r = t >> 2, c0 = (t & 3) * 16;
  const u16* arow = xb + (tm * 64 + r) * 768;
  const u16* brow = qw + (tn * 64 + r) * 768;
  for (int k0 = 0; k0 < 768; k0 += 64) {
    int4 a0, a1, b0, b1;
    ld16g(&a0, arow + k0 + c0); ld16g(&a1, arow + k0 + c0 + 8);
    ld16g(&b0, brow + k0 + c0); ld16g(&b1, brow + k0 + c0 + 8);
    __builtin_memcpy(&At[r][c0], &a0, 16); __builtin_memcpy(&At[r][c0 + 8], &a1, 16);
    __builtin_memcpy(&Bt[r][c0], &b0, 16); __builtin_memcpy(&Bt[r][c0 + 8], &b1, 16);
    __syncthreads();
    for (int ks = 0; ks < 2; ks++) {
      bf16x8 a = ldfrag(&At[w * 16 + l15][ks * 32 + g * 8]);
#pragma unroll
      for (int ct = 0; ct < 4; ct++) {
        bf16x8 b = ldfrag(&Bt[ct * 16 + l15][ks * 32 + g * 8]);
        acc[ct] = mfma_(a, b, acc[ct]);
      }
    }
    __syncthreads();
  }
  float sq = sums[0] * (1.f / NQ) * 0.180336880111120f;  // * 0.125 * log2(e)
  float sk = sums[1] * (1.f / NK);
  float sv = sums[2] * (1.f / NK);
  int mbase = tm * 64 + w * 16 + g * 4;
  if (tn < 18) {
    float sc = (tn < 12) ? sq : sk;
    int head = (tn < 12) ? tn : tn - 12;
    u16* outp = (tn < 12) ? qb : kb;
    int stride = (tn < 12) ? 768 : 384;
#pragma unroll
    for (int ct = 0; ct < 2; ct++) {
      int i = ct * 16 + l15;
      float f = (float)pow(10000.0, -(double)i * (1.0 / 32.0));
      for (int rr = 0; rr < 4; rr++) {
        int m = mbase + rr; int s = m & 2047;
        float ang = (float)s * f;
        float sn, cs; sincosf(ang, &sn, &cs);
        float x1 = acc[ct][rr] * sc, x2 = acc[ct + 2][rr] * sc;
        outp[m * stride + head * 64 + i]      = f2bf(x1 * cs - x2 * sn);
        outp[m * stride + head * 64 + i + 32] = f2bf(x2 * cs + x1 * sn);
      }
    }
  } else {
    int kvh = tn - 18;
#pragma unroll
    for (int ct = 0; ct < 4; ct++) {
      int d = ct * 16 + l15;
      for (int rr = 0; rr < 4; rr++) {
        int m = mbase + rr; int bb = m >> 11; int s = m & 2047;
        vT[((bb * 6 + kvh) * 64 + d) * 2048 + s] = f2bf(acc[ct][rr] * sv);
      }
    }
  }
}

// ---------- 5) attention: LDS-free streaming softmax, 32x32 MFMA, barrier-free main loop ----------
// grid (32 q-tiles of 64 rows, 24 b*h). block 256 = 4 waves; wave w handles keys [w*512, w*512+512).
// S^T = K Q^T so C-layout col = q = PV A-frag m index; C->A needs only lane^32 half-exchange.
__global__ __launch_bounds__(256, 2) void attn_kernel(const u16* __restrict__ qb, const u16* __restrict__ kb,
                                                      const u16* __restrict__ vT, u16* __restrict__ ab) {
  __shared__ float Obuf[4][64][68];
  __shared__ float Lbuf[4][64];
  int qt = blockIdx.x, bh = blockIdx.y;
  int b = bh / 12, h = bh % 12, kvh = h >> 1;
  int t = threadIdx.x, lane = t & 63, w = t >> 6, c = lane & 31, g2 = lane >> 5;

  // Preload Q B-frags (already scaled by 0.125*log2e): B[n=q=lane&31][k=d=ks*16+8*g2+j]
  const u16* qbase = qb + (b * 2048 + qt * 64) * 768 + h * 64;
  bf16x8 qf[2][4];
#pragma unroll
  for (int qn = 0; qn < 2; qn++)
#pragma unroll
    for (int ks = 0; ks < 4; ks++)
      qf[qn][ks] = ldfrag(qbase + (qn * 32 + c) * 768 + ks * 16 + 8 * g2);

  f32x16 fz = {0,0,0,0,0,0,0,0,0,0,0,0,0,0,0,0};
  f32x16 O[2][2] = {{fz, fz}, {fz, fz}};   // [qn][dn]
  float lsum[2] = {0.f, 0.f};

  const u16* kbase = kb + (b * 2048) * 384 + kvh * 64;
  const u16* vbase = vT + ((b * 6 + kvh) * 64) * 2048;

  for (int it = 0; it < 8; it++) {
    int key0 = w * 512 + it * 64;
    // K A-frags: A[m=key][k=d]
    bf16x8 kf[2][4];
#pragma unroll
    for (int km = 0; km < 2; km++)
#pragma unroll
      for (int ks = 0; ks < 4; ks++)
        kf[km][ks] = ldfrag(kbase + (key0 + km * 32 + c) * 384 + ks * 16 + 8 * g2);
    // S^T[km][qn]: rows = keys, cols = q
    f32x16 S[2][2] = {{fz, fz}, {fz, fz}};
#pragma unroll
    for (int ks = 0; ks < 4; ks++)
#pragma unroll
      for (int km = 0; km < 2; km++)
#pragma unroll
        for (int qn = 0; qn < 2; qn++)
          S[km][qn] = mfma32_(kf[km][ks], qf[qn][ks], S[km][qn]);
    // V B-frags: B[n=d][k=key] from vT[d][s]
    bf16x8 vf[2][4];
#pragma unroll
    for (int dn = 0; dn < 2; dn++)
#pragma unroll
      for (int ks = 0; ks < 4; ks++)
        vf[dn][ks] = ldfrag(vbase + (dn * 32 + c) * 2048 + key0 + ks * 16 + 8 * g2);
    // exp2 -> pack bf16 pairs -> lane^32 exchange -> PV A-frags PA[qn][0..3]
    bf16x8 PA[2][4];
#pragma unroll
    for (int qn = 0; qn < 2; qn++) {
#pragma unroll
      for (int km = 0; km < 2; km++) {
        float e[16];
#pragma unroll
        for (int r = 0; r < 16; r++) {
          e[r] = fexp2(S[km][qn][r]);
          lsum[qn] += e[r];
        }
        u32 P[8];
#pragma unroll
        for (int j = 0; j < 8; j++) P[j] = packbf(e[2 * j], e[2 * j + 1]);
        // kstep t=0 within tile: lane g2=0 needs partner P[0],P[1]; sends P[2],P[3]
        u32 X0a = (u32)__shfl_xor((int)(g2 == 0 ? P[2] : P[0]), 32);
        u32 X0b = (u32)__shfl_xor((int)(g2 == 0 ? P[3] : P[1]), 32);
        u32 X1a = (u32)__shfl_xor((int)(g2 == 0 ? P[6] : P[4]), 32);
        u32 X1b = (u32)__shfl_xor((int)(g2 == 0 ? P[7] : P[5]), 32);
        u32 f0[4], f1[4];
        if (g2 == 0) { f0[0]=P[0]; f0[1]=P[1]; f0[2]=X0a; f0[3]=X0b; f1[0]=P[4]; f1[1]=P[5]; f1[2]=X1a; f1[3]=X1b; }
        else         { f0[0]=X0a; f0[1]=X0b; f0[2]=P[2]; f0[3]=P[3]; f1[0]=X1a; f1[1]=X1b; f1[2]=P[6]; f1[3]=P[7]; }
        __builtin_memcpy(&PA[qn][km * 2 + 0], f0, 16);
        __builtin_memcpy(&PA[qn][km * 2 + 1], f1, 16);
      }
    }
    // O[qn][dn] += P * V^T
#pragma unroll
    for (int ks = 0; ks < 4; ks++)
#pragma unroll
      for (int qn = 0; qn < 2; qn++)
#pragma unroll
        for (int dn = 0; dn < 2; dn++)
          O[qn][dn] = mfma32_(PA[qn][ks], vf[dn][ks], O[qn][dn]);
  }
  // combine across the 4 key-split waves via LDS
#pragma unroll
  for (int qn = 0; qn < 2; qn++) {
    lsum[qn] += __shfl_xor(lsum[qn], 32);
#pragma unroll
    for (int dn = 0; dn < 2; dn++)
#pragma unroll
      for (int r = 0; r < 16; r++) {
        int q = qn * 32 + (r & 3) + 8 * (r >> 2) + 4 * g2;
        Obuf[w][q][dn * 32 + c] = O[qn][dn][r];
      }
  }
  if (g2 == 0) {
    Lbuf[w][0 * 32 + c] = lsum[0];
    Lbuf[w][1 * 32 + c] = lsum[1];
  }
  __syncthreads();
  // epilogue: thread t -> q = t>>2, 16 d values
  {
    int q = t >> 2, dc = (t & 3) * 16;
    float l = Lbuf[0][q] + Lbuf[1][q] + Lbuf[2][q] + Lbuf[3][q];
    float inv = 1.f / l;
    u16 o[16];
#pragma unroll
    for (int j = 0; j < 16; j++) {
      float s = Obuf[0][q][dc + j] + Obuf[1][q][dc + j] + Obuf[2][q][dc + j] + Obuf[3][q][dc + j];
      o[j] = f2bf(s * inv);
    }
    u16* dst = ab + (b * 2048 + qt * 64 + q) * 768 + h * 64 + dc;
    __builtin_memcpy(dst, o, 16);
    __builtin_memcpy(dst + 8, o + 8, 16);
  }
}

// ---------- 6) output projection GEMM -> fp32 ----------
__global__ __launch_bounds__(256) void gemm_out_kernel(const u16* __restrict__ ab, const u16* __restrict__ woq,
                                                       const float* __restrict__ sums, float* __restrict__ out) {
  __shared__ u16 At[64][72];
  __shared__ u16 Bt[64][72];
  int tn = blockIdx.x, tm = blockIdx.y;
  int t = threadIdx.x, lane = t & 63, w = t >> 6, l15 = lane & 15, g = lane >> 4;
  f32x4 zero = {0.f, 0.f, 0.f, 0.f};
  f32x4 acc[4] = {zero, zero, zero, zero};
  int r = t >> 2, c0 = (t & 3) * 16;
  const u16* arow = ab + (tm * 64 + r) * 768;
  const u16* brow = woq + (tn * 64 + r) * 768;
  for (int k0 = 0; k0 < 768; k0 += 64) {
    int4 a0, a1, b0, b1;
    ld16g(&a0, arow + k0 + c0); ld16g(&a1, arow + k0 + c0 + 8);
    ld16g(&b0, brow + k0 + c0); ld16g(&b1, brow + k0 + c0 + 8);
    __builtin_memcpy(&At[r][c0], &a0, 16); __builtin_memcpy(&At[r][c0 + 8], &a1, 16);
    __builtin_memcpy(&Bt[r][c0], &b0, 16); __builtin_memcpy(&Bt[r][c0 + 8], &b1, 16);
    __syncthreads();
    for (int ks = 0; ks < 2; ks++) {
      bf16x8 a = ldfrag(&At[w * 16 + l15][ks * 32 + g * 8]);
#pragma unroll
      for (int ct = 0; ct < 4; ct++) {
        bf16x8 b = ldfrag(&Bt[ct * 16 + l15][ks * 32 + g * 8]);
        acc[ct] = mfma_(a, b, acc[ct]);
      }
    }
    __syncthreads();
  }
  float so = sums[3] * (1.f / NQ);
  int mbase = tm * 64 + w * 16 + g * 4;
#pragma unroll
  for (int ct = 0; ct < 4; ct++)
    for (int rr = 0; rr < 4; rr++)
      out[(mbase + rr) * 768 + tn * 64 + ct * 16 + l15] = acc[ct][rr] * so;
}

// ---------- launch ----------
extern "C" void kernel_launch(void* const* d_in, const int* in_sizes, int n_in,
                              void* d_out, int out_size, void* d_ws, size_t ws_size,
                              hipStream_t stream) {
  const float* x  = (const float*)d_in[0];
  const float* wq = (const float*)d_in[1];
  const float* wk = (const float*)d_in[2];
  const float* wv = (const float*)d_in[3];
  const float* wo = (const float*)d_in[4];
  float* out = (float*)d_out;
  char* ws = (char*)d_ws;

  float* sums = (float*)ws;                    // 16 B
  u16* qw  = (u16*)(ws + 256);                 // [1536][768]
  u16* woq = (u16*)(ws + 2359552);             // [768][768]
  u16* xb  = (u16*)(ws + 3539200);             // [4096][768]
  u16* qb  = (u16*)(ws + 9830656);             // [4096][768]
  u16* kb  = (u16*)(ws + 16122112);            // [4096][384]
  u16* vT  = (u16*)(ws + 19267840);            // [2*6][64][2048]
  u16* ab  = (u16*)(ws + 22413568);            // [4096][768]

  hipMemsetAsync(sums, 0, 16, stream);
  dim3 blk(256);
  abssum_kernel<<<dim3(64, 4), blk, 0, stream>>>(wq, wk, wv, wo, sums);
  quant_kernel<<<dim3(6912), blk, 0, stream>>>(wq, wk, wv, wo, sums, qw, woq);
  castx_kernel<<<dim3(3072), blk, 0, stream>>>(x, xb);
  gemm_qkv_kernel<<<dim3(24, 64), blk, 0, stream>>>(xb, qw, sums, qb, kb, vT);
  attn_kernel<<<dim3(32, 24), blk, 0, stream>>>(qb, kb, vT, ab);
  gemm_out_kernel<<<dim3(12, 64), blk, 0, stream>>>(ab, woq, sums, out);
}